// Round 3
// baseline (793.905 us; speedup 1.0000x reference)
//
#include <hip/hip_runtime.h>
#include <hip/hip_bf16.h>

#define BATCH   65536
#define NCHAN   12
#define LRAW    63
#define CHF     168
#define FLEN    7
#define VLEN    57
#define FGH     35
#define EN1     16
#define EN2     32
#define KWID    6
#define LC1     18
#define LC2     5

// ---- workspace layout (floats): small buffers FIRST, big c1 LAST ----
static const size_t WS_STATS = 0;                               // 96: bn1_s[16] bn1_q[16] bn2_s[32] bn2_q[32]
static const size_t WS_COEF  = 96;                              // 96: a1[16] b1[16] a2[32] b2[32]
static const size_t WS_W1T   = 192;                             // 1152: enc_w1 as [c][j][oc]
static const size_t WS_W2T   = WS_W1T + 1152;                   // 3072: enc_w2 as [c][j][oc]
static const size_t WS_FILT  = WS_W2T + 3072;                   // BATCH*8 (16-byte aligned: 4416*4)
static const size_t WS_C1    = WS_FILT + (size_t)BATCH * 8;     // BATCH*288 (c2 aliases first 160 of each slot)

// K0: zero stats, transpose conv weights to oc-contiguous layout for uniform scalar loads
__global__ void k_init(const float* __restrict__ ew1, const float* __restrict__ ew2,
                       float* __restrict__ w1t, float* __restrict__ w2t,
                       float* __restrict__ stats) {
    int t = threadIdx.x;
    if (t < 96) stats[t] = 0.f;
    for (int i = t; i < EN1 * NCHAN * KWID; i += 256) {      // 1152
        int oc = i / (NCHAN * KWID); int r = i % (NCHAN * KWID);
        w1t[r * EN1 + oc] = ew1[i];
    }
    for (int i = t; i < EN2 * EN1 * KWID; i += 256) {        // 3072
        int oc = i / (EN1 * KWID); int r = i % (EN1 * KWID);
        w2t[r * EN2 + oc] = ew2[i];
    }
}

// K1: filter generator MLP, one sample per lane, single pass over eegf
__global__ __launch_bounds__(256) void k_fg(
        const float* __restrict__ eegf,
        const float* __restrict__ w1, const float* __restrict__ b1,
        const float* __restrict__ w2, const float* __restrict__ b2,
        float* __restrict__ filt) {
    int b = blockIdx.x * 256 + threadIdx.x;
    const float* xr = eegf + (size_t)b * CHF;
    float acc[FGH];
#pragma unroll
    for (int j = 0; j < FGH; j++) acc[j] = b1[j];
#pragma unroll 1
    for (int t0 = 0; t0 < CHF; t0 += 56) {                   // 3 i-tiles, eegf read ONCE
        float x[56];
#pragma unroll
        for (int q = 0; q < 14; q++) {
            float4 v = *reinterpret_cast<const float4*>(xr + t0 + 4 * q);
            x[4*q] = v.x; x[4*q+1] = v.y; x[4*q+2] = v.z; x[4*q+3] = v.w;
        }
#pragma unroll 1
        for (int j = 0; j < FGH; j++) {
            const float* wr = w1 + (size_t)j * CHF + t0;     // uniform -> scalar loads
            float s = 0.f;
#pragma unroll
            for (int q = 0; q < 56; q++) s = fmaf(x[q], wr[q], s);
            acc[j] += s;
        }
    }
    float fa[FLEN];
#pragma unroll
    for (int k = 0; k < FLEN; k++) fa[k] = b2[k];
#pragma unroll 1
    for (int j = 0; j < FGH; j++) {
        float h = tanhf(acc[j]);
#pragma unroll
        for (int k = 0; k < FLEN; k++) fa[k] = fmaf(h, w2[k * FGH + j], fa[k]);
    }
    float4 o0, o1;
    o0.x = tanhf(fa[0]); o0.y = tanhf(fa[1]); o0.z = tanhf(fa[2]); o0.w = tanhf(fa[3]);
    o1.x = tanhf(fa[4]); o1.y = tanhf(fa[5]); o1.z = tanhf(fa[6]); o1.w = 0.f;
    float4* fo = reinterpret_cast<float4*>(filt + (size_t)b * 8);
    fo[0] = o0; fo[1] = o1;
}

// K2: adaptive depthwise filter -> eeg (LDS), conv1, BN1 stats  (LDS = 44.4 KB)
__global__ __launch_bounds__(256) void k_conv1(
        const float* __restrict__ raw, const float* __restrict__ encb1,
        const float* __restrict__ filtbuf, const float* __restrict__ w1t,
        float* __restrict__ c1, float* __restrict__ stats) {
    __shared__ float eegs[16 * 685];      // [s][c][t] stride 685; later aliased as c1t [s*305 + oc*19 + p]
    __shared__ float filts[16][8];
    const int tid = threadIdx.x;
    const int s0 = blockIdx.x * 16;
    if (tid < 128)
        filts[tid >> 3][tid & 7] = filtbuf[(size_t)(s0 + (tid >> 3)) * 8 + (tid & 7)];
    __syncthreads();
    // phase D: 192 threads compute eeg rows via sliding 7-register window
    if (tid < 192) {
        const int s = tid / 12, c = tid % 12;
        const float* r = raw + ((size_t)(s0 + s) * NCHAN + c) * LRAW;
        const float f0 = filts[s][0], f1 = filts[s][1], f2 = filts[s][2], f3 = filts[s][3],
                    f4 = filts[s][4], f5 = filts[s][5], f6 = filts[s][6];
        float a[7];
#pragma unroll
        for (int k = 0; k < 7; k++) a[k] = r[k];
        float* eb = eegs + s * 685 + c * 57;
#pragma unroll 1
        for (int t = 0; t < 56; t += 7) {
#pragma unroll
            for (int u = 0; u < 7; u++) {
                float v = f0 * a[(u + 0) % 7];
                v = fmaf(f1, a[(u + 1) % 7], v);
                v = fmaf(f2, a[(u + 2) % 7], v);
                v = fmaf(f3, a[(u + 3) % 7], v);
                v = fmaf(f4, a[(u + 4) % 7], v);
                v = fmaf(f5, a[(u + 5) % 7], v);
                v = fmaf(f6, a[(u + 6) % 7], v);
                eb[t + u] = v;
                a[u] = r[t + 7 + u];
            }
        }
        {   // t = 56 (window r[56..62] sits in a[0..6] in order)
            float v = f0 * a[0];
            v = fmaf(f1, a[1], v); v = fmaf(f2, a[2], v); v = fmaf(f3, a[3], v);
            v = fmaf(f4, a[4], v); v = fmaf(f5, a[5], v); v = fmaf(f6, a[6], v);
            eb[56] = v;
        }
    }
    __syncthreads();
    // conv1: thread = (s = tid&15, p = tid>>4); threads <32 take a second task p+16
    const int sA = tid & 15;
    const int pA = tid >> 4;
    const bool two = (tid < 32);
    const int pB = 16 + (tid >> 4);
    float acc[EN1], acc2[EN1];
#pragma unroll
    for (int o = 0; o < EN1; o++) { float bv = encb1[o]; acc[o] = bv; acc2[o] = bv; }
    const float* eA = eegs + sA * 685;
#pragma unroll 1
    for (int c = 0; c < NCHAN; c++) {
#pragma unroll
        for (int j = 0; j < KWID; j++) {
            float ev = eA[c * 57 + 3 * pA + j];
            const float* wp = w1t + (c * KWID + j) * EN1;   // uniform address -> s_load
#pragma unroll
            for (int o = 0; o < EN1; o++) acc[o] = fmaf(ev, wp[o], acc[o]);
        }
    }
    if (two) {
#pragma unroll 1
        for (int c = 0; c < NCHAN; c++) {
#pragma unroll
            for (int j = 0; j < KWID; j++) {
                float ev = eA[c * 57 + 3 * pB + j];
                const float* wp = w1t + (c * KWID + j) * EN1;
#pragma unroll
                for (int o = 0; o < EN1; o++) acc2[o] = fmaf(ev, wp[o], acc2[o]);
            }
        }
    }
    __syncthreads();                       // all eeg reads complete; alias as c1t
    float* c1t = eegs;                     // [s*305 + oc*19 + p]
#pragma unroll
    for (int o = 0; o < EN1; o++) c1t[sA * 305 + o * 19 + pA] = acc[o];
    if (two) {
#pragma unroll
        for (int o = 0; o < EN1; o++) c1t[sA * 305 + o * 19 + pB] = acc2[o];
    }
    __syncthreads();
    // coalesced global write of the 16x16x18 tile
    float* c1g = c1 + (size_t)s0 * 288;
#pragma unroll 1
    for (int k = 0; k < 18; k++) {
        int idx = tid + k * 256;
        int s = idx / 288, f = idx % 288;
        int oc = f / 18, p = f % 18;
        c1g[idx] = c1t[s * 305 + oc * 19 + p];
    }
    // BN1 stats: thread = (oc = tid>>4, g = tid&15); shuffle-reduce over 16-lane groups
    {
        const int oc = tid >> 4, g = tid & 15;
        float sm = 0.f, sq = 0.f;
#pragma unroll
        for (int p = 0; p < 18; p++) {
            float v = c1t[g * 305 + oc * 19 + p];
            sm += v; sq = fmaf(v, v, sq);
        }
#pragma unroll
        for (int m = 8; m >= 1; m >>= 1) {
            sm += __shfl_xor(sm, m);
            sq += __shfl_xor(sq, m);
        }
        if (g == 0) {
            atomicAdd(stats + oc, sm);
            atomicAdd(stats + 16 + oc, sq);
        }
    }
}

// K3/K5: finalize batchnorm coefficients  a = g*rsqrt(var+eps), b = beta - mean*a
__global__ void k_bnfin(const float* __restrict__ g, const float* __restrict__ bb,
                        const float* __restrict__ s, const float* __restrict__ q,
                        float* __restrict__ ca, float* __restrict__ cb,
                        int nch, float invn) {
    int t = threadIdx.x;
    if (t < nch) {
        float mean = s[t] * invn;
        float var  = q[t] * invn - mean * mean;
        float a = g[t] * rsqrtf(var + 1e-5f);
        ca[t] = a;
        cb[t] = bb[t] - mean * a;
    }
}

// K4: BN1+tanh on c1 (staged to LDS), conv2, BN2 stats; c2 written into c1 slots
// 32 samples/block -> LDS 36,992 B (safely under 64 KB static limit)
__global__ __launch_bounds__(256) void k_conv2(
        const float* __restrict__ encb2, const float* __restrict__ bn1c,
        const float* __restrict__ w2t, float* __restrict__ c1,
        float* __restrict__ stats2) {
    __shared__ float e1s[32 * 289];        // [s*289 + c*18 + t]; later aliased as c2t [s*161 + oc*5 + p]
    const int tid = threadIdx.x;
    const int s0 = blockIdx.x * 32;
    float* c1g = c1 + (size_t)s0 * 288;
#pragma unroll 1
    for (int k = 0; k < 36; k++) {         // 9216 = 32*288, exact
        int idx = tid + k * 256;
        int s = idx / 288, f = idx % 288, ch = f / 18;
        float v = c1g[idx];
        e1s[s * 289 + f] = tanhf(fmaf(v, bn1c[ch], bn1c[16 + ch]));
    }
    __syncthreads();
    const int s = tid & 31, p = tid >> 5;  // p in 0..7, active p<5
    float acc[EN2];
#pragma unroll
    for (int o = 0; o < EN2; o++) acc[o] = encb2[o];
    if (p < 5) {
        const float* eS = e1s + s * 289;
#pragma unroll 1
        for (int c = 0; c < EN1; c++) {
#pragma unroll
            for (int j = 0; j < KWID; j++) {
                float ev = eS[c * 18 + 3 * p + j];
                const float* wp = w2t + (c * KWID + j) * EN2;   // uniform -> s_load
#pragma unroll
                for (int o = 0; o < EN2; o++) acc[o] = fmaf(ev, wp[o], acc[o]);
            }
        }
    }
    __syncthreads();                       // e1 reads done; alias as c2t
    float* c2t = e1s;
    if (p < 5) {
#pragma unroll
        for (int o = 0; o < EN2; o++) c2t[s * 161 + o * 5 + p] = acc[o];
    }
    __syncthreads();
    // coalesced c2 write into the head of each sample's 288-slot
#pragma unroll 1
    for (int k = 0; k < 20; k++) {
        int idx = tid + k * 256;           // 5120 = 32*160, exact
        int ss = idx / 160, f = idx % 160;
        c1g[(size_t)ss * 288 + f] = c2t[ss * 161 + f];
    }
    // BN2 stats: oc = tid>>3 (0..31), g = tid&7, 4 samples each
    {
        const int oc = tid >> 3, g = tid & 7;
        float sm = 0.f, sq = 0.f;
#pragma unroll 1
        for (int mm = 0; mm < 4; mm++) {
            int ss = g + 8 * mm;
#pragma unroll
            for (int pp = 0; pp < 5; pp++) {
                float v = c2t[ss * 161 + oc * 5 + pp];
                sm += v; sq = fmaf(v, v, sq);
            }
        }
#pragma unroll
        for (int m = 4; m >= 1; m >>= 1) {
            sm += __shfl_xor(sm, m);
            sq += __shfl_xor(sq, m);
        }
        if (g == 0) {
            atomicAdd(stats2 + oc, sm);        // bn2 sums at stats[32..]
            atomicAdd(stats2 + 32 + oc, sq);   // bn2 sumsq at stats[64..]
        }
    }
}

// K6: BN2+tanh streamed into mu/logvar dots, reparameterize, decoder, outputs
__global__ __launch_bounds__(256) void k_head(
        const float* __restrict__ eps,
        const float* __restrict__ muw, const float* __restrict__ mub,
        const float* __restrict__ lvw, const float* __restrict__ lvb,
        const float* __restrict__ dw1, const float* __restrict__ db1,
        const float* __restrict__ dw2, const float* __restrict__ db2,
        const float* __restrict__ c2, const float* __restrict__ bn2c,
        float* __restrict__ out) {
    int b = blockIdx.x * 256 + threadIdx.x;
    const float4* c2v = reinterpret_cast<const float4*>(c2 + (size_t)b * 288);
    float m0 = mub[0], m1 = mub[1], l0 = lvb[0], l1 = lvb[1];
#pragma unroll 1
    for (int qq = 0; qq < 40; qq++) {
        float4 v = c2v[qq];
#pragma unroll
        for (int u = 0; u < 4; u++) {
            int idx = 4 * qq + u;
            int ch = idx / 5;
            float x = (u == 0) ? v.x : (u == 1) ? v.y : (u == 2) ? v.z : v.w;
            float h = tanhf(fmaf(x, bn2c[ch], bn2c[32 + ch]));
            m0 = fmaf(h, muw[idx],       m0);
            m1 = fmaf(h, muw[160 + idx], m1);
            l0 = fmaf(h, lvw[idx],       l0);
            l1 = fmaf(h, lvw[160 + idx], l1);
        }
    }
    float2 ev = *reinterpret_cast<const float2*>(eps + (size_t)b * 2);
    float z0 = fmaf(ev.x, expf(0.5f * l0), m0);
    float z1 = fmaf(ev.y, expf(0.5f * l1), m1);
    float d[10];
#pragma unroll
    for (int j = 0; j < 10; j++)
        d[j] = tanhf(fmaf(z1, dw1[j * 2 + 1], fmaf(z0, dw1[j * 2], db1[j])));
    float* orow = out + (size_t)b * 50;
#pragma unroll 1
    for (int o = 0; o < 50; o += 2) {
        float s0 = db2[o], s1 = db2[o + 1];
#pragma unroll
        for (int j = 0; j < 10; j++) {
            s0 = fmaf(d[j], dw2[o * 10 + j],       s0);
            s1 = fmaf(d[j], dw2[(o + 1) * 10 + j], s1);
        }
        float2 w; w.x = tanhf(s0); w.y = tanhf(s1);
        *reinterpret_cast<float2*>(orow + o) = w;
    }
    *reinterpret_cast<float2*>(out + (size_t)BATCH * 50 + (size_t)b * 2) = make_float2(m0, m1);
    *reinterpret_cast<float2*>(out + (size_t)BATCH * 52 + (size_t)b * 2) = make_float2(l0, l1);
}

extern "C" void kernel_launch(void* const* d_in, const int* in_sizes, int n_in,
                              void* d_out, int out_size, void* d_ws, size_t ws_size,
                              hipStream_t stream) {
    (void)in_sizes; (void)n_in; (void)out_size; (void)ws_size;
    const float* raw  = (const float*)d_in[0];
    const float* eegf = (const float*)d_in[1];
    const float* eps  = (const float*)d_in[2];
    const float* fgw1 = (const float*)d_in[3];
    const float* fgb1 = (const float*)d_in[4];
    const float* fgw2 = (const float*)d_in[5];
    const float* fgb2 = (const float*)d_in[6];
    const float* ew1  = (const float*)d_in[7];
    const float* eb1  = (const float*)d_in[8];
    const float* bn1g = (const float*)d_in[9];
    const float* bn1b = (const float*)d_in[10];
    const float* ew2  = (const float*)d_in[11];
    const float* eb2  = (const float*)d_in[12];
    const float* bn2g = (const float*)d_in[13];
    const float* bn2b = (const float*)d_in[14];
    const float* muw  = (const float*)d_in[15];
    const float* mub  = (const float*)d_in[16];
    const float* lvw  = (const float*)d_in[17];
    const float* lvb  = (const float*)d_in[18];
    const float* dw1  = (const float*)d_in[19];
    const float* db1  = (const float*)d_in[20];
    const float* dw2  = (const float*)d_in[21];
    const float* db2  = (const float*)d_in[22];

    float* ws    = (float*)d_ws;
    float* stats = ws + WS_STATS;
    float* coef  = ws + WS_COEF;
    float* w1t   = ws + WS_W1T;
    float* w2t   = ws + WS_W2T;
    float* filt  = ws + WS_FILT;
    float* c1    = ws + WS_C1;
    float* out   = (float*)d_out;

    hipLaunchKernelGGL(k_init, dim3(1), dim3(256), 0, stream, ew1, ew2, w1t, w2t, stats);
    hipLaunchKernelGGL(k_fg, dim3(256), dim3(256), 0, stream, eegf, fgw1, fgb1, fgw2, fgb2, filt);
    hipLaunchKernelGGL(k_conv1, dim3(4096), dim3(256), 0, stream, raw, eb1, filt, w1t, c1, stats);
    hipLaunchKernelGGL(k_bnfin, dim3(1), dim3(64), 0, stream,
                       bn1g, bn1b, stats, stats + 16, coef, coef + 16,
                       16, 1.0f / ((float)BATCH * (float)LC1));
    hipLaunchKernelGGL(k_conv2, dim3(2048), dim3(256), 0, stream, eb2, coef, w2t, c1, stats + 32);
    hipLaunchKernelGGL(k_bnfin, dim3(1), dim3(64), 0, stream,
                       bn2g, bn2b, stats + 32, stats + 64, coef + 32, coef + 64,
                       32, 1.0f / ((float)BATCH * (float)LC2));
    hipLaunchKernelGGL(k_head, dim3(256), dim3(256), 0, stream,
                       eps, muw, mub, lvw, lvb, dw1, db1, dw2, db2, c1, coef + 32, out);
}

// Round 4
// 752.391 us; speedup vs baseline: 1.0552x; 1.0552x over previous
//
#include <hip/hip_runtime.h>
#include <hip/hip_bf16.h>

#define BATCH   65536
#define NCHAN   12
#define LRAW    63
#define CHF     168
#define FLEN    7
#define VLEN    57
#define FGH     35
#define EN1     16
#define EN2     32
#define KWID    6
#define LC1     18
#define LC2     5

// ---- workspace layout (floats): small buffers FIRST, big c1 LAST ----
static const size_t WS_STATS = 0;                               // 96
static const size_t WS_COEF  = 96;                              // 96
static const size_t WS_W1T   = 192;                             // 1152
static const size_t WS_W2T   = WS_W1T + 1152;                   // 3072
static const size_t WS_FILT  = WS_W2T + 3072;                   // BATCH*8
static const size_t WS_C1    = WS_FILT + (size_t)BATCH * 8;     // BATCH*288

// K0: zero stats, transpose conv weights to oc-contiguous layout
__global__ void k_init(const float* __restrict__ ew1, const float* __restrict__ ew2,
                       float* __restrict__ w1t, float* __restrict__ w2t,
                       float* __restrict__ stats) {
    int t = threadIdx.x;
    if (t < 96) stats[t] = 0.f;
    for (int i = t; i < EN1 * NCHAN * KWID; i += 256) {
        int oc = i / (NCHAN * KWID); int r = i % (NCHAN * KWID);
        w1t[r * EN1 + oc] = ew1[i];
    }
    for (int i = t; i < EN2 * EN1 * KWID; i += 256) {
        int oc = i / (EN1 * KWID); int r = i % (EN1 * KWID);
        w2t[r * EN2 + oc] = ew2[i];
    }
}

// K1: filter generator MLP, one sample per lane, 4-way split dot chains
__global__ __launch_bounds__(256) void k_fg(
        const float* __restrict__ eegf,
        const float* __restrict__ w1, const float* __restrict__ b1,
        const float* __restrict__ w2, const float* __restrict__ b2,
        float* __restrict__ filt) {
    int b = blockIdx.x * 256 + threadIdx.x;
    const float* xr = eegf + (size_t)b * CHF;
    float acc[FGH];
#pragma unroll
    for (int j = 0; j < FGH; j++) acc[j] = b1[j];
#pragma unroll 1
    for (int t0 = 0; t0 < CHF; t0 += 56) {
        float x[56];
#pragma unroll
        for (int q = 0; q < 14; q++) {
            float4 v = *reinterpret_cast<const float4*>(xr + t0 + 4 * q);
            x[4*q] = v.x; x[4*q+1] = v.y; x[4*q+2] = v.z; x[4*q+3] = v.w;
        }
#pragma unroll 1
        for (int j = 0; j < FGH; j++) {
            const float* wr = w1 + (size_t)j * CHF + t0;     // uniform -> s_load
            float s0 = 0.f, s1 = 0.f, s2 = 0.f, s3 = 0.f;
#pragma unroll
            for (int q = 0; q < 14; q++) {
                s0 = fmaf(x[4*q],   wr[4*q],   s0);
                s1 = fmaf(x[4*q+1], wr[4*q+1], s1);
                s2 = fmaf(x[4*q+2], wr[4*q+2], s2);
                s3 = fmaf(x[4*q+3], wr[4*q+3], s3);
            }
            acc[j] += (s0 + s1) + (s2 + s3);
        }
    }
    float fa[FLEN];
#pragma unroll
    for (int k = 0; k < FLEN; k++) fa[k] = b2[k];
#pragma unroll 1
    for (int j = 0; j < FGH; j++) {
        float h = tanhf(acc[j]);
#pragma unroll
        for (int k = 0; k < FLEN; k++) fa[k] = fmaf(h, w2[k * FGH + j], fa[k]);
    }
    float4 o0, o1;
    o0.x = tanhf(fa[0]); o0.y = tanhf(fa[1]); o0.z = tanhf(fa[2]); o0.w = tanhf(fa[3]);
    o1.x = tanhf(fa[4]); o1.y = tanhf(fa[5]); o1.z = tanhf(fa[6]); o1.w = 0.f;
    float4* fo = reinterpret_cast<float4*>(filt + (size_t)b * 8);
    fo[0] = o0; fo[1] = o1;
}

// K2: coalesced LDS staging of raw, on-the-fly adaptive filter + conv1, BN1 stats
// 16 samples/block, 320 threads, LDS ~48.9 KB -> 3 blocks/CU
__global__ __launch_bounds__(320) void k_conv1(
        const float* __restrict__ raw, const float* __restrict__ encb1,
        const float* __restrict__ filtbuf, const float* __restrict__ w1t,
        float* __restrict__ c1, float* __restrict__ stats) {
    __shared__ float4 rawt4[3024];          // 16 samples x 756 floats (aliased later as c1t)
    __shared__ float filts[16][9];          // padded to 9 -> bank-clean broadcast
    float* rawt = (float*)rawt4;
    const int tid = threadIdx.x;
    const int s0b = blockIdx.x * 16;
    // stage: contiguous, fully coalesced float4 copy (48,384 B)
    const float4* src4 = reinterpret_cast<const float4*>(raw + (size_t)s0b * 756);
#pragma unroll
    for (int k = 0; k < 10; k++) {
        int idx = tid + k * 320;
        if (idx < 3024) rawt4[idx] = src4[idx];
    }
    if (tid < 112) {                        // 16 samples x 7 taps
        int s = tid / 7, k = tid % 7;
        filts[s][k] = filtbuf[(size_t)(s0b + s) * 8 + k];
    }
    __syncthreads();
    // conv: thread = (s = tid&15, p = tid>>4 in 0..19, active p<18)
    const int s = tid & 15;
    const int pg = tid >> 4;
    float acc[EN1];
#pragma unroll
    for (int o = 0; o < EN1; o++) acc[o] = encb1[o];
    if (pg < 18) {
        const float f0 = filts[s][0], f1 = filts[s][1], f2 = filts[s][2], f3 = filts[s][3],
                    f4 = filts[s][4], f5 = filts[s][5], f6 = filts[s][6];
        const float* rbase = rawt + s * 756 + 3 * pg;
#pragma unroll 1
        for (int c = 0; c < NCHAN; c++) {
            const float* rp = rbase + c * 63;
            float rv[12];
#pragma unroll
            for (int j = 0; j < 12; j++) rv[j] = rp[j];
            float e[KWID];
#pragma unroll
            for (int j = 0; j < KWID; j++) {
                float v = f0 * rv[j];
                v = fmaf(f1, rv[j+1], v);
                v = fmaf(f2, rv[j+2], v);
                v = fmaf(f3, rv[j+3], v);
                v = fmaf(f4, rv[j+4], v);
                v = fmaf(f5, rv[j+5], v);
                v = fmaf(f6, rv[j+6], v);
                e[j] = v;
            }
            const float* wp = w1t + c * (KWID * EN1);        // uniform -> s_load
#pragma unroll
            for (int j = 0; j < KWID; j++)
#pragma unroll
                for (int o = 0; o < EN1; o++)
                    acc[o] = fmaf(e[j], wp[j * EN1 + o], acc[o]);
        }
    }
    __syncthreads();                        // all rawt reads done; alias as c1t
    float* c1t = rawt;                      // [s*305 + oc*19 + p]
    if (pg < 18) {
#pragma unroll
        for (int o = 0; o < EN1; o++) c1t[s * 305 + o * 19 + pg] = acc[o];
    }
    __syncthreads();
    // coalesced global write: 16 rows of 288
    float* c1g = c1 + (size_t)s0b * 288;
#pragma unroll 1
    for (int ss = 0; ss < 16; ss++) {
        if (tid < 288) {
            int oc = tid / 18, p = tid - oc * 18;
            c1g[ss * 288 + tid] = c1t[ss * 305 + oc * 19 + p];
        }
    }
    // BN1 stats
    if (tid < 256) {
        const int oc = tid >> 4, g = tid & 15;
        float sm = 0.f, sq = 0.f;
#pragma unroll
        for (int p = 0; p < 18; p++) {
            float v = c1t[g * 305 + oc * 19 + p];
            sm += v; sq = fmaf(v, v, sq);
        }
#pragma unroll
        for (int m = 8; m >= 1; m >>= 1) {
            sm += __shfl_xor(sm, m);
            sq += __shfl_xor(sq, m);
        }
        if (g == 0) {
            atomicAdd(stats + oc, sm);
            atomicAdd(stats + 16 + oc, sq);
        }
    }
}

// K3/K5: finalize batchnorm coefficients
__global__ void k_bnfin(const float* __restrict__ g, const float* __restrict__ bb,
                        const float* __restrict__ s, const float* __restrict__ q,
                        float* __restrict__ ca, float* __restrict__ cb,
                        int nch, float invn) {
    int t = threadIdx.x;
    if (t < nch) {
        float mean = s[t] * invn;
        float var  = q[t] * invn - mean * mean;
        float a = g[t] * rsqrtf(var + 1e-5f);
        ca[t] = a;
        cb[t] = bb[t] - mean * a;
    }
}

// K4: BN1+tanh staged to LDS (float4, div-free), conv2, BN2 stats; c2 into c1 slots
__global__ __launch_bounds__(256) void k_conv2(
        const float* __restrict__ encb2, const float* __restrict__ bn1c,
        const float* __restrict__ w2t, float* __restrict__ c1,
        float* __restrict__ stats2) {
    __shared__ float e1s[32 * 289];         // later aliased as c2t [s*161 + oc*5 + p]
    const int tid = threadIdx.x;
    const int s0b = blockIdx.x * 32;
    float* c1g = c1 + (size_t)s0b * 288;
    const int sl = tid >> 3, g = tid & 7;   // 32 samples x 8 lanes
    // stage + BN1 + tanh: each 8-lane group handles one row (72 float4)
    {
        const float4* row4 = reinterpret_cast<const float4*>(c1g + sl * 288);
#pragma unroll 1
        for (int kk = 0; kk < 9; kk++) {
            int fo = kk * 8 + g;            // float4 idx 0..71
            float4 v = row4[fo];
            float r[4] = {v.x, v.y, v.z, v.w};
            int i0 = fo * 4;
#pragma unroll
            for (int u = 0; u < 4; u++) {
                int i = i0 + u;
                int ch = i / 18;            // const-div -> magic mul
                e1s[sl * 289 + i] = tanhf(fmaf(r[u], bn1c[ch], bn1c[16 + ch]));
            }
        }
    }
    __syncthreads();
    // conv2: s = tid&31, p = tid>>5 (0..7, active p<5)
    const int s = tid & 31, p = tid >> 5;
    float acc[EN2];
#pragma unroll
    for (int o = 0; o < EN2; o++) acc[o] = encb2[o];
    if (p < 5) {
        const float* eS = e1s + s * 289;
#pragma unroll 1
        for (int c = 0; c < EN1; c++) {
#pragma unroll
            for (int j = 0; j < KWID; j++) {
                float ev = eS[c * 18 + 3 * p + j];
                const float* wp = w2t + (c * KWID + j) * EN2;   // uniform -> s_load
#pragma unroll
                for (int o = 0; o < EN2; o++) acc[o] = fmaf(ev, wp[o], acc[o]);
            }
        }
    }
    __syncthreads();                        // e1 reads done; alias as c2t
    float* c2t = e1s;
    if (p < 5) {
#pragma unroll
        for (int o = 0; o < EN2; o++) c2t[s * 161 + o * 5 + p] = acc[o];
    }
    __syncthreads();
    // writeback c2 (160 floats) into head of each sample's 288-slot, float4 stores
    {
        float4* row4 = reinterpret_cast<float4*>(c1g + sl * 288);
#pragma unroll 1
        for (int kk = 0; kk < 5; kk++) {
            int fo = kk * 8 + g;            // 0..39
            int i0 = fo * 4;
            float4 w;
            w.x = c2t[sl * 161 + i0];
            w.y = c2t[sl * 161 + i0 + 1];
            w.z = c2t[sl * 161 + i0 + 2];
            w.w = c2t[sl * 161 + i0 + 3];
            row4[fo] = w;
        }
    }
    // BN2 stats: oc = tid>>3 (0..31), g8 = tid&7, 4 samples each
    {
        const int oc = tid >> 3, g8 = tid & 7;
        float sm = 0.f, sq = 0.f;
#pragma unroll 1
        for (int mm = 0; mm < 4; mm++) {
            int ss = g8 + 8 * mm;
#pragma unroll
            for (int pp = 0; pp < 5; pp++) {
                float v = c2t[ss * 161 + oc * 5 + pp];
                sm += v; sq = fmaf(v, v, sq);
            }
        }
#pragma unroll
        for (int m = 4; m >= 1; m >>= 1) {
            sm += __shfl_xor(sm, m);
            sq += __shfl_xor(sq, m);
        }
        if (g8 == 0) {
            atomicAdd(stats2 + oc, sm);
            atomicAdd(stats2 + 32 + oc, sq);
        }
    }
}

// K6: 4 lanes per sample; BN2+tanh streamed into mu/logvar dots, reparam, decoder
__global__ __launch_bounds__(256) void k_head(
        const float* __restrict__ eps,
        const float* __restrict__ muw, const float* __restrict__ mub,
        const float* __restrict__ lvw, const float* __restrict__ lvb,
        const float* __restrict__ dw1, const float* __restrict__ db1,
        const float* __restrict__ dw2, const float* __restrict__ db2,
        const float* __restrict__ c2, const float* __restrict__ bn2c,
        float* __restrict__ out) {
    int gid = blockIdx.x * 256 + threadIdx.x;
    int b = gid >> 2, q = gid & 3;
    const float4* c2v = reinterpret_cast<const float4*>(c2 + (size_t)b * 288 + q * 40);
    float m0 = 0.f, m1 = 0.f, l0 = 0.f, l1 = 0.f;
#pragma unroll 1
    for (int t = 0; t < 10; t++) {
        float4 v = c2v[t];
        float r[4] = {v.x, v.y, v.z, v.w};
#pragma unroll
        for (int u = 0; u < 4; u++) {
            int idx = q * 40 + t * 4 + u;
            int ch = idx / 5;
            float h = tanhf(fmaf(r[u], bn2c[ch], bn2c[32 + ch]));
            m0 = fmaf(h, muw[idx],       m0);
            m1 = fmaf(h, muw[160 + idx], m1);
            l0 = fmaf(h, lvw[idx],       l0);
            l1 = fmaf(h, lvw[160 + idx], l1);
        }
    }
#pragma unroll
    for (int m = 1; m <= 2; m <<= 1) {
        m0 += __shfl_xor(m0, m); m1 += __shfl_xor(m1, m);
        l0 += __shfl_xor(l0, m); l1 += __shfl_xor(l1, m);
    }
    m0 += mub[0]; m1 += mub[1]; l0 += lvb[0]; l1 += lvb[1];
    float2 ev = *reinterpret_cast<const float2*>(eps + (size_t)b * 2);
    float z0 = fmaf(ev.x, expf(0.5f * l0), m0);
    float z1 = fmaf(ev.y, expf(0.5f * l1), m1);
    float d[10];
#pragma unroll
    for (int j = 0; j < 10; j++)
        d[j] = tanhf(fmaf(z1, dw1[j * 2 + 1], fmaf(z0, dw1[j * 2], db1[j])));
    float* orow = out + (size_t)b * 50;
    int nkk = (q == 3) ? 7 : 6;             // 25 float2 chunks split 6/6/6/7
#pragma unroll 1
    for (int kk = 0; kk < nkk; kk++) {
        int o = (q * 6 + kk) * 2;
        float s0 = db2[o], s1 = db2[o + 1];
#pragma unroll
        for (int j = 0; j < 10; j++) {
            s0 = fmaf(d[j], dw2[o * 10 + j],       s0);
            s1 = fmaf(d[j], dw2[(o + 1) * 10 + j], s1);
        }
        float2 w; w.x = tanhf(s0); w.y = tanhf(s1);
        *reinterpret_cast<float2*>(orow + o) = w;
    }
    if (q == 0)
        *reinterpret_cast<float2*>(out + (size_t)BATCH * 50 + (size_t)b * 2) = make_float2(m0, m1);
    if (q == 1)
        *reinterpret_cast<float2*>(out + (size_t)BATCH * 52 + (size_t)b * 2) = make_float2(l0, l1);
}

extern "C" void kernel_launch(void* const* d_in, const int* in_sizes, int n_in,
                              void* d_out, int out_size, void* d_ws, size_t ws_size,
                              hipStream_t stream) {
    (void)in_sizes; (void)n_in; (void)out_size; (void)ws_size;
    const float* raw  = (const float*)d_in[0];
    const float* eegf = (const float*)d_in[1];
    const float* eps  = (const float*)d_in[2];
    const float* fgw1 = (const float*)d_in[3];
    const float* fgb1 = (const float*)d_in[4];
    const float* fgw2 = (const float*)d_in[5];
    const float* fgb2 = (const float*)d_in[6];
    const float* ew1  = (const float*)d_in[7];
    const float* eb1  = (const float*)d_in[8];
    const float* bn1g = (const float*)d_in[9];
    const float* bn1b = (const float*)d_in[10];
    const float* ew2  = (const float*)d_in[11];
    const float* eb2  = (const float*)d_in[12];
    const float* bn2g = (const float*)d_in[13];
    const float* bn2b = (const float*)d_in[14];
    const float* muw  = (const float*)d_in[15];
    const float* mub  = (const float*)d_in[16];
    const float* lvw  = (const float*)d_in[17];
    const float* lvb  = (const float*)d_in[18];
    const float* dw1  = (const float*)d_in[19];
    const float* db1  = (const float*)d_in[20];
    const float* dw2  = (const float*)d_in[21];
    const float* db2  = (const float*)d_in[22];

    float* ws    = (float*)d_ws;
    float* stats = ws + WS_STATS;
    float* coef  = ws + WS_COEF;
    float* w1t   = ws + WS_W1T;
    float* w2t   = ws + WS_W2T;
    float* filt  = ws + WS_FILT;
    float* c1    = ws + WS_C1;
    float* out   = (float*)d_out;

    hipLaunchKernelGGL(k_init, dim3(1), dim3(256), 0, stream, ew1, ew2, w1t, w2t, stats);
    hipLaunchKernelGGL(k_fg, dim3(256), dim3(256), 0, stream, eegf, fgw1, fgb1, fgw2, fgb2, filt);
    hipLaunchKernelGGL(k_conv1, dim3(4096), dim3(320), 0, stream, raw, eb1, filt, w1t, c1, stats);
    hipLaunchKernelGGL(k_bnfin, dim3(1), dim3(64), 0, stream,
                       bn1g, bn1b, stats, stats + 16, coef, coef + 16,
                       16, 1.0f / ((float)BATCH * (float)LC1));
    hipLaunchKernelGGL(k_conv2, dim3(2048), dim3(256), 0, stream, eb2, coef, w2t, c1, stats + 32);
    hipLaunchKernelGGL(k_bnfin, dim3(1), dim3(64), 0, stream,
                       bn2g, bn2b, stats + 32, stats + 64, coef + 32, coef + 64,
                       32, 1.0f / ((float)BATCH * (float)LC2));
    hipLaunchKernelGGL(k_head, dim3(1024), dim3(256), 0, stream,
                       eps, muw, mub, lvw, lvb, dw1, db1, dw2, db2, c1, coef + 32, out);
}

// Round 6
// 629.898 us; speedup vs baseline: 1.2604x; 1.1945x over previous
//
#include <hip/hip_runtime.h>
#include <hip/hip_bf16.h>

#define BATCH   65536
#define NCHAN   12
#define LRAW    63
#define CHF     168
#define FLEN    7
#define VLEN    57
#define FGH     35
#define EN1     16
#define EN2     32
#define KWID    6
#define LC1     18
#define LC2     5

#define SH1     64      // bn1 stat shards (4096 blocks -> 64 blocks/shard)
#define SH2     32      // bn2 stat shards (2048 blocks -> 64 blocks/shard)

// ---- workspace layout (floats): small buffers FIRST, big c1 LAST ----
static const size_t WS_STATS1 = 0;                                // SH1*32 = 2048
static const size_t WS_STATS2 = 2048;                             // SH2*64 = 2048
static const size_t WS_COEF   = 4096;                             // 96: a1[16] b1[16] a2[32] b2[32]
static const size_t WS_W1T    = 4192;                             // 1152
static const size_t WS_W2T    = WS_W1T + 1152;                    // 3072
static const size_t WS_FILT   = WS_W2T + 3072;                    // BATCH*8
static const size_t WS_C1     = WS_FILT + (size_t)BATCH * 8;      // BATCH*288

// K0: zero shard stats, transpose conv weights to oc-contiguous layout
__global__ void k_init(const float* __restrict__ ew1, const float* __restrict__ ew2,
                       float* __restrict__ w1t, float* __restrict__ w2t,
                       float* __restrict__ stats) {
    int t = threadIdx.x;
    for (int i = t; i < 4096; i += 256) stats[i] = 0.f;          // stats1+stats2
    for (int i = t; i < EN1 * NCHAN * KWID; i += 256) {
        int oc = i / (NCHAN * KWID); int r = i % (NCHAN * KWID);
        w1t[r * EN1 + oc] = ew1[i];
    }
    for (int i = t; i < EN2 * EN1 * KWID; i += 256) {
        int oc = i / (EN1 * KWID); int r = i % (EN1 * KWID);
        w2t[r * EN2 + oc] = ew2[i];
    }
}

// K1: filter generator MLP, one sample per lane, 4-way split dot chains
__global__ __launch_bounds__(256) void k_fg(
        const float* __restrict__ eegf,
        const float* __restrict__ w1, const float* __restrict__ b1,
        const float* __restrict__ w2, const float* __restrict__ b2,
        float* __restrict__ filt) {
    int b = blockIdx.x * 256 + threadIdx.x;
    const float* xr = eegf + (size_t)b * CHF;
    float acc[FGH];
#pragma unroll
    for (int j = 0; j < FGH; j++) acc[j] = b1[j];
#pragma unroll 1
    for (int t0 = 0; t0 < CHF; t0 += 56) {
        float x[56];
#pragma unroll
        for (int q = 0; q < 14; q++) {
            float4 v = *reinterpret_cast<const float4*>(xr + t0 + 4 * q);
            x[4*q] = v.x; x[4*q+1] = v.y; x[4*q+2] = v.z; x[4*q+3] = v.w;
        }
#pragma unroll 1
        for (int j = 0; j < FGH; j++) {
            const float* wr = w1 + (size_t)j * CHF + t0;     // uniform -> s_load
            float s0 = 0.f, s1 = 0.f, s2 = 0.f, s3 = 0.f;
#pragma unroll
            for (int q = 0; q < 14; q++) {
                s0 = fmaf(x[4*q],   wr[4*q],   s0);
                s1 = fmaf(x[4*q+1], wr[4*q+1], s1);
                s2 = fmaf(x[4*q+2], wr[4*q+2], s2);
                s3 = fmaf(x[4*q+3], wr[4*q+3], s3);
            }
            acc[j] += (s0 + s1) + (s2 + s3);
        }
    }
    float fa[FLEN];
#pragma unroll
    for (int k = 0; k < FLEN; k++) fa[k] = b2[k];
#pragma unroll 1
    for (int j = 0; j < FGH; j++) {
        float h = tanhf(acc[j]);
#pragma unroll
        for (int k = 0; k < FLEN; k++) fa[k] = fmaf(h, w2[k * FGH + j], fa[k]);
    }
    float4 o0, o1;
    o0.x = tanhf(fa[0]); o0.y = tanhf(fa[1]); o0.z = tanhf(fa[2]); o0.w = tanhf(fa[3]);
    o1.x = tanhf(fa[4]); o1.y = tanhf(fa[5]); o1.z = tanhf(fa[6]); o1.w = 0.f;
    float4* fo = reinterpret_cast<float4*>(filt + (size_t)b * 8);
    fo[0] = o0; fo[1] = o1;
}

// K2: coalesced LDS staging of raw, on-the-fly adaptive filter + conv1, BN1 stats (sharded)
__global__ __launch_bounds__(320) void k_conv1(
        const float* __restrict__ raw, const float* __restrict__ encb1,
        const float* __restrict__ filtbuf, const float* __restrict__ w1t,
        float* __restrict__ c1, float* __restrict__ stats1) {
    __shared__ float4 rawt4[3024];          // 16 samples x 756 floats (aliased later as c1t)
    __shared__ float filts[16][9];
    float* rawt = (float*)rawt4;
    const int tid = threadIdx.x;
    const int s0b = blockIdx.x * 16;
    const float4* src4 = reinterpret_cast<const float4*>(raw + (size_t)s0b * 756);
#pragma unroll
    for (int k = 0; k < 10; k++) {
        int idx = tid + k * 320;
        if (idx < 3024) rawt4[idx] = src4[idx];
    }
    if (tid < 112) {
        int s = tid / 7, k = tid % 7;
        filts[s][k] = filtbuf[(size_t)(s0b + s) * 8 + k];
    }
    __syncthreads();
    const int s = tid & 15;
    const int pg = tid >> 4;
    float acc[EN1];
#pragma unroll
    for (int o = 0; o < EN1; o++) acc[o] = encb1[o];
    if (pg < 18) {
        const float f0 = filts[s][0], f1 = filts[s][1], f2 = filts[s][2], f3 = filts[s][3],
                    f4 = filts[s][4], f5 = filts[s][5], f6 = filts[s][6];
        const float* rbase = rawt + s * 756 + 3 * pg;
#pragma unroll 1
        for (int c = 0; c < NCHAN; c++) {
            const float* rp = rbase + c * 63;
            float rv[12];
#pragma unroll
            for (int j = 0; j < 12; j++) rv[j] = rp[j];
            float e[KWID];
#pragma unroll
            for (int j = 0; j < KWID; j++) {
                float v = f0 * rv[j];
                v = fmaf(f1, rv[j+1], v);
                v = fmaf(f2, rv[j+2], v);
                v = fmaf(f3, rv[j+3], v);
                v = fmaf(f4, rv[j+4], v);
                v = fmaf(f5, rv[j+5], v);
                v = fmaf(f6, rv[j+6], v);
                e[j] = v;
            }
            const float* wp = w1t + c * (KWID * EN1);        // uniform -> s_load
#pragma unroll
            for (int j = 0; j < KWID; j++)
#pragma unroll
                for (int o = 0; o < EN1; o++)
                    acc[o] = fmaf(e[j], wp[j * EN1 + o], acc[o]);
        }
    }
    __syncthreads();
    float* c1t = rawt;                      // [s*305 + oc*19 + p]
    if (pg < 18) {
#pragma unroll
        for (int o = 0; o < EN1; o++) c1t[s * 305 + o * 19 + pg] = acc[o];
    }
    __syncthreads();
    float* c1g = c1 + (size_t)s0b * 288;
#pragma unroll 1
    for (int ss = 0; ss < 16; ss++) {
        if (tid < 288) {
            int oc = tid / 18, p = tid - oc * 18;
            c1g[ss * 288 + tid] = c1t[ss * 305 + oc * 19 + p];
        }
    }
    // BN1 stats -> sharded accumulators (64 shards x one 128B line each)
    if (tid < 256) {
        const int oc = tid >> 4, g = tid & 15;
        float sm = 0.f, sq = 0.f;
#pragma unroll
        for (int p = 0; p < 18; p++) {
            float v = c1t[g * 305 + oc * 19 + p];
            sm += v; sq = fmaf(v, v, sq);
        }
#pragma unroll
        for (int m = 8; m >= 1; m >>= 1) {
            sm += __shfl_xor(sm, m);
            sq += __shfl_xor(sq, m);
        }
        if (g == 0) {
            float* base = stats1 + (blockIdx.x & (SH1 - 1)) * 32;
            atomicAdd(base + oc, sm);
            atomicAdd(base + 16 + oc, sq);
        }
    }
}

// K3/K5: reduce shards, finalize batchnorm coefficients
// shards layout: [nsh][2*nch] (sum at +c, sumsq at +nch+c)
__global__ void k_bnfin(const float* __restrict__ g, const float* __restrict__ bb,
                        const float* __restrict__ shards, int nsh, int nch,
                        float* __restrict__ ca, float* __restrict__ cb,
                        float invn) {
    int t = threadIdx.x;
    if (t < nch) {
        float sm = 0.f, sq = 0.f;
        for (int i = 0; i < nsh; i++) {
            sm += shards[i * 2 * nch + t];
            sq += shards[i * 2 * nch + nch + t];
        }
        float mean = sm * invn;
        float var  = sq * invn - mean * mean;
        float a = g[t] * rsqrtf(var + 1e-5f);
        ca[t] = a;
        cb[t] = bb[t] - mean * a;
    }
}

// K4: BN1+tanh staged to LDS, conv2, BN2 stats (sharded); c2 into c1 slots
__global__ __launch_bounds__(256) void k_conv2(
        const float* __restrict__ encb2, const float* __restrict__ bn1c,
        const float* __restrict__ w2t, float* __restrict__ c1,
        float* __restrict__ stats2) {
    __shared__ float e1s[32 * 289];
    const int tid = threadIdx.x;
    const int s0b = blockIdx.x * 32;
    float* c1g = c1 + (size_t)s0b * 288;
    const int sl = tid >> 3, g = tid & 7;
    {
        const float4* row4 = reinterpret_cast<const float4*>(c1g + sl * 288);
#pragma unroll 1
        for (int kk = 0; kk < 9; kk++) {
            int fo = kk * 8 + g;
            float4 v = row4[fo];
            float r[4] = {v.x, v.y, v.z, v.w};
            int i0 = fo * 4;
#pragma unroll
            for (int u = 0; u < 4; u++) {
                int i = i0 + u;
                int ch = i / 18;
                e1s[sl * 289 + i] = tanhf(fmaf(r[u], bn1c[ch], bn1c[16 + ch]));
            }
        }
    }
    __syncthreads();
    const int s = tid & 31, p = tid >> 5;
    float acc[EN2];
#pragma unroll
    for (int o = 0; o < EN2; o++) acc[o] = encb2[o];
    if (p < 5) {
        const float* eS = e1s + s * 289;
#pragma unroll 1
        for (int c = 0; c < EN1; c++) {
#pragma unroll
            for (int j = 0; j < KWID; j++) {
                float ev = eS[c * 18 + 3 * p + j];
                const float* wp = w2t + (c * KWID + j) * EN2;
#pragma unroll
                for (int o = 0; o < EN2; o++) acc[o] = fmaf(ev, wp[o], acc[o]);
            }
        }
    }
    __syncthreads();
    float* c2t = e1s;
    if (p < 5) {
#pragma unroll
        for (int o = 0; o < EN2; o++) c2t[s * 161 + o * 5 + p] = acc[o];
    }
    __syncthreads();
    {
        float4* row4 = reinterpret_cast<float4*>(c1g + sl * 288);
#pragma unroll 1
        for (int kk = 0; kk < 5; kk++) {
            int fo = kk * 8 + g;
            int i0 = fo * 4;
            float4 w;
            w.x = c2t[sl * 161 + i0];
            w.y = c2t[sl * 161 + i0 + 1];
            w.z = c2t[sl * 161 + i0 + 2];
            w.w = c2t[sl * 161 + i0 + 3];
            row4[fo] = w;
        }
    }
    // BN2 stats -> sharded accumulators (32 shards x 64 floats)
    {
        const int oc = tid >> 3, g8 = tid & 7;
        float sm = 0.f, sq = 0.f;
#pragma unroll 1
        for (int mm = 0; mm < 4; mm++) {
            int ss = g8 + 8 * mm;
#pragma unroll
            for (int pp = 0; pp < 5; pp++) {
                float v = c2t[ss * 161 + oc * 5 + pp];
                sm += v; sq = fmaf(v, v, sq);
            }
        }
#pragma unroll
        for (int m = 4; m >= 1; m >>= 1) {
            sm += __shfl_xor(sm, m);
            sq += __shfl_xor(sq, m);
        }
        if (g8 == 0) {
            float* base = stats2 + (blockIdx.x & (SH2 - 1)) * 64;
            atomicAdd(base + oc, sm);
            atomicAdd(base + 32 + oc, sq);
        }
    }
}

// K6: 4 lanes per sample; BN2+tanh streamed into mu/logvar dots, reparam, decoder
__global__ __launch_bounds__(256) void k_head(
        const float* __restrict__ eps,
        const float* __restrict__ muw, const float* __restrict__ mub,
        const float* __restrict__ lvw, const float* __restrict__ lvb,
        const float* __restrict__ dw1, const float* __restrict__ db1,
        const float* __restrict__ dw2, const float* __restrict__ db2,
        const float* __restrict__ c2, const float* __restrict__ bn2c,
        float* __restrict__ out) {
    int gid = blockIdx.x * 256 + threadIdx.x;
    int b = gid >> 2, q = gid & 3;
    const float4* c2v = reinterpret_cast<const float4*>(c2 + (size_t)b * 288 + q * 40);
    float m0 = 0.f, m1 = 0.f, l0 = 0.f, l1 = 0.f;
#pragma unroll 1
    for (int t = 0; t < 10; t++) {
        float4 v = c2v[t];
        float r[4] = {v.x, v.y, v.z, v.w};
#pragma unroll
        for (int u = 0; u < 4; u++) {
            int idx = q * 40 + t * 4 + u;
            int ch = idx / 5;
            float h = tanhf(fmaf(r[u], bn2c[ch], bn2c[32 + ch]));
            m0 = fmaf(h, muw[idx],       m0);
            m1 = fmaf(h, muw[160 + idx], m1);
            l0 = fmaf(h, lvw[idx],       l0);
            l1 = fmaf(h, lvw[160 + idx], l1);
        }
    }
#pragma unroll
    for (int m = 1; m <= 2; m <<= 1) {
        m0 += __shfl_xor(m0, m); m1 += __shfl_xor(m1, m);
        l0 += __shfl_xor(l0, m); l1 += __shfl_xor(l1, m);
    }
    m0 += mub[0]; m1 += mub[1]; l0 += lvb[0]; l1 += lvb[1];
    float2 ev = *reinterpret_cast<const float2*>(eps + (size_t)b * 2);
    float z0 = fmaf(ev.x, expf(0.5f * l0), m0);
    float z1 = fmaf(ev.y, expf(0.5f * l1), m1);
    float d[10];
#pragma unroll
    for (int j = 0; j < 10; j++)
        d[j] = tanhf(fmaf(z1, dw1[j * 2 + 1], fmaf(z0, dw1[j * 2], db1[j])));
    float* orow = out + (size_t)b * 50;
    int nkk = (q == 3) ? 7 : 6;
#pragma unroll 1
    for (int kk = 0; kk < nkk; kk++) {
        int o = (q * 6 + kk) * 2;
        float s0 = db2[o], s1 = db2[o + 1];
#pragma unroll
        for (int j = 0; j < 10; j++) {
            s0 = fmaf(d[j], dw2[o * 10 + j],       s0);
            s1 = fmaf(d[j], dw2[(o + 1) * 10 + j], s1);
        }
        float2 w; w.x = tanhf(s0); w.y = tanhf(s1);
        *reinterpret_cast<float2*>(orow + o) = w;
    }
    if (q == 0)
        *reinterpret_cast<float2*>(out + (size_t)BATCH * 50 + (size_t)b * 2) = make_float2(m0, m1);
    if (q == 1)
        *reinterpret_cast<float2*>(out + (size_t)BATCH * 52 + (size_t)b * 2) = make_float2(l0, l1);
}

extern "C" void kernel_launch(void* const* d_in, const int* in_sizes, int n_in,
                              void* d_out, int out_size, void* d_ws, size_t ws_size,
                              hipStream_t stream) {
    (void)in_sizes; (void)n_in; (void)out_size; (void)ws_size;
    const float* raw  = (const float*)d_in[0];
    const float* eegf = (const float*)d_in[1];
    const float* eps  = (const float*)d_in[2];
    const float* fgw1 = (const float*)d_in[3];
    const float* fgb1 = (const float*)d_in[4];
    const float* fgw2 = (const float*)d_in[5];
    const float* fgb2 = (const float*)d_in[6];
    const float* ew1  = (const float*)d_in[7];
    const float* eb1  = (const float*)d_in[8];
    const float* bn1g = (const float*)d_in[9];
    const float* bn1b = (const float*)d_in[10];
    const float* ew2  = (const float*)d_in[11];
    const float* eb2  = (const float*)d_in[12];
    const float* bn2g = (const float*)d_in[13];
    const float* bn2b = (const float*)d_in[14];
    const float* muw  = (const float*)d_in[15];
    const float* mub  = (const float*)d_in[16];
    const float* lvw  = (const float*)d_in[17];
    const float* lvb  = (const float*)d_in[18];
    const float* dw1  = (const float*)d_in[19];
    const float* db1  = (const float*)d_in[20];
    const float* dw2  = (const float*)d_in[21];
    const float* db2  = (const float*)d_in[22];

    float* ws     = (float*)d_ws;
    float* stats1 = ws + WS_STATS1;
    float* stats2 = ws + WS_STATS2;
    float* coef   = ws + WS_COEF;
    float* w1t    = ws + WS_W1T;
    float* w2t    = ws + WS_W2T;
    float* filt   = ws + WS_FILT;
    float* c1     = ws + WS_C1;
    float* out    = (float*)d_out;

    hipLaunchKernelGGL(k_init, dim3(1), dim3(256), 0, stream, ew1, ew2, w1t, w2t, stats1);
    hipLaunchKernelGGL(k_fg, dim3(256), dim3(256), 0, stream, eegf, fgw1, fgb1, fgw2, fgb2, filt);
    hipLaunchKernelGGL(k_conv1, dim3(4096), dim3(320), 0, stream, raw, eb1, filt, w1t, c1, stats1);
    hipLaunchKernelGGL(k_bnfin, dim3(1), dim3(64), 0, stream,
                       bn1g, bn1b, stats1, SH1, 16, coef, coef + 16,
                       1.0f / ((float)BATCH * (float)LC1));
    hipLaunchKernelGGL(k_conv2, dim3(2048), dim3(256), 0, stream, eb2, coef, w2t, c1, stats2);
    hipLaunchKernelGGL(k_bnfin, dim3(1), dim3(64), 0, stream,
                       bn2g, bn2b, stats2, SH2, 32, coef + 32, coef + 64,
                       1.0f / ((float)BATCH * (float)LC2));
    hipLaunchKernelGGL(k_head, dim3(1024), dim3(256), 0, stream,
                       eps, muw, mub, lvw, lvb, dw1, db1, dw2, db2, c1, coef + 32, out);
}